// Round 1
// baseline (289.447 us; speedup 1.0000x reference)
//
#include <hip/hip_runtime.h>

#define H 4096
#define W 4096
#define TILE 64
#define LD_DIM 68            // TILE + 4 (halo of 2 on each side)
#define LD_STRIDE 69         // +1 pad, odd stride -> no LDS bank conflicts
#define LB_DIM 66            // TILE + 2 (halo of 1 on each side)
#define LB_STRIDE 67
#define ALPHA 0.2

__device__ __forceinline__ int reflect_idx(int i, int n) {
    // BORDER_REFLECT_101; offsets here are at most 2 beyond the border
    if (i < 0) return -i;
    if (i >= n) return 2 * n - 2 - i;
    return i;
}

__global__ __launch_bounds__(256)
void loss_main(const float* __restrict__ pred,
               const float* __restrict__ target,
               double* __restrict__ acc) {
    __shared__ float LD[LD_DIM * LD_STRIDE];   // d = t - p, global reflect baked in
    __shared__ float LB[LB_DIM * LB_STRIDE];   // gaussian(d), 2nd-level reflect baked in
    __shared__ double wsum[4][3];

    const int bx = blockIdx.x & 63;            // W/TILE = 64
    const int by = blockIdx.x >> 6;
    const int i0 = by * TILE;
    const int j0 = bx * TILE;
    const int tid = threadIdx.x;

    float s_d2 = 0.f;   // sum of diff^2 over valid owned pixels
    float s_cnt = 0.f;  // count of valid owned pixels
    float s_y  = 0.f;   // sum of G over owned pixels

    // ---- Stage 1: load d into LDS (with reflect); MSE on owned pixels ----
    for (int e = tid; e < LD_DIM * LD_DIM; e += 256) {
        int y = e / LD_DIM;
        int x = e - y * LD_DIM;
        int gy = i0 - 2 + y;
        int gx = j0 - 2 + x;
        int ry = reflect_idx(gy, H);
        int rx = reflect_idx(gx, W);
        float t = target[ry * W + rx];
        float p = pred[ry * W + rx];
        float d = t - p;
        LD[y * LD_STRIDE + x] = d;
        // owned center: each global pixel is owned by exactly one block
        if (y >= 2 && y < 2 + TILE && x >= 2 && x < 2 + TILE) {
            if (t > 0.f) { s_d2 += d * d; s_cnt += 1.f; }
        }
    }
    __syncthreads();

    // ---- Stage 2: LB[y][x] = B(R(i0-1+y), R(j0-1+x)), B = 3x3 gaussian of d ----
    for (int e = tid; e < LB_DIM * LB_DIM; e += 256) {
        int y = e / LB_DIM;
        int x = e - y * LB_DIM;
        int r = reflect_idx(i0 - 1 + y, H);    // valid B row index
        int c = reflect_idx(j0 - 1 + x, W);
        int ly = r - (i0 - 2);                 // LDS coords of d(r, c)
        int lx = c - (j0 - 2);
        float b = 0.f;
        #pragma unroll
        for (int a = -1; a <= 1; ++a) {
            float wy = (a == 0) ? 0.5f : 0.25f;
            const float* row = &LD[(ly + a) * LD_STRIDE + lx];
            float rs = 0.25f * row[-1] + 0.5f * row[0] + 0.25f * row[1];
            b += wy * rs;
        }
        LB[y * LB_STRIDE + x] = b;
    }
    __syncthreads();

    // ---- Stage 3: Y(i,j) = LB(yy+2,xx+2) - LB(yy+2,xx) - LB(yy,xx+2) + LB(yy,xx) ----
    for (int e = tid; e < TILE * TILE; e += 256) {
        int yy = e >> 6;
        int xx = e & 63;
        const float* rm = &LB[yy * LB_STRIDE + xx];
        const float* rp = &LB[(yy + 2) * LB_STRIDE + xx];
        s_y += (rp[2] - rp[0]) - (rm[2] - rm[0]);
    }

    // ---- Block reduction (wave64 shuffle, then cross-wave via LDS) ----
    #pragma unroll
    for (int off = 32; off > 0; off >>= 1) {
        s_d2 += __shfl_down(s_d2, off);
        s_cnt += __shfl_down(s_cnt, off);
        s_y  += __shfl_down(s_y, off);
    }
    const int wave = tid >> 6;
    const int lane = tid & 63;
    if (lane == 0) {
        wsum[wave][0] = (double)s_d2;
        wsum[wave][1] = (double)s_cnt;
        wsum[wave][2] = (double)s_y;
    }
    __syncthreads();
    if (tid == 0) {
        double a0 = wsum[0][0] + wsum[1][0] + wsum[2][0] + wsum[3][0];
        double a1 = wsum[0][1] + wsum[1][1] + wsum[2][1] + wsum[3][1];
        double a2 = wsum[0][2] + wsum[1][2] + wsum[2][2] + wsum[3][2];
        atomicAdd(&acc[0], a0);
        atomicAdd(&acc[1], a1);
        atomicAdd(&acc[2], a2);
    }
}

__global__ void loss_final(const double* __restrict__ acc, float* __restrict__ out) {
    double mse   = acc[0] / fmax(acc[1], 1.0);
    double meanG = acc[2] / ((double)H * (double)W);
    out[0] = (float)(ALPHA * meanG + (1.0 - ALPHA) * mse);
}

extern "C" void kernel_launch(void* const* d_in, const int* in_sizes, int n_in,
                              void* d_out, int out_size, void* d_ws, size_t ws_size,
                              hipStream_t stream) {
    const float* pred   = (const float*)d_in[0];
    const float* target = (const float*)d_in[1];
    float* out = (float*)d_out;
    double* acc = (double*)d_ws;

    hipMemsetAsync(acc, 0, 3 * sizeof(double), stream);

    dim3 grid((H / TILE) * (W / TILE));
    loss_main<<<grid, 256, 0, stream>>>(pred, target, acc);
    loss_final<<<1, 1, 0, stream>>>(acc, out);
}

// Round 2
// 186.831 us; speedup vs baseline: 1.5492x; 1.5492x over previous
//
#include <hip/hip_runtime.h>

#define H 4096
#define W 4096
#define ALPHA 0.2
#define NBLK 2048

__device__ __forceinline__ int reflect_idx(int i, int n) {
    if (i < 0) return -i;              // reflect-101, |offset| <= 1 here
    if (i >= n) return 2 * n - 2 - i;
    return i;
}

// acc[0] = sum of (t-p)^2 over valid (t>0); acc[1] = valid count
__global__ __launch_bounds__(256)
void mse_kernel(const float4* __restrict__ pred,
                const float4* __restrict__ target,
                double* __restrict__ acc) {
    const int N4 = (H * W) / 4;                 // 4,194,304
    const int nthreads = NBLK * 256;            // 524,288 -> 8 iters/thread
    float s = 0.f;
    int cnt = 0;
    for (int i = blockIdx.x * 256 + threadIdx.x; i < N4; i += nthreads) {
        float4 t = target[i];
        float4 p = pred[i];
        float dx = t.x - p.x, dy = t.y - p.y, dz = t.z - p.z, dw = t.w - p.w;
        if (t.x > 0.f) { s += dx * dx; cnt++; }
        if (t.y > 0.f) { s += dy * dy; cnt++; }
        if (t.z > 0.f) { s += dz * dz; cnt++; }
        if (t.w > 0.f) { s += dw * dw; cnt++; }
    }
    #pragma unroll
    for (int off = 32; off > 0; off >>= 1) {
        s += __shfl_down(s, off);
        cnt += __shfl_down(cnt, off);
    }
    __shared__ double ws[4][2];
    const int wave = threadIdx.x >> 6;
    const int lane = threadIdx.x & 63;
    if (lane == 0) { ws[wave][0] = (double)s; ws[wave][1] = (double)cnt; }
    __syncthreads();
    if (threadIdx.x == 0) {
        atomicAdd(&acc[0], ws[0][0] + ws[1][0] + ws[2][0] + ws[3][0]);
        atomicAdd(&acc[1], ws[0][1] + ws[1][1] + ws[2][1] + ws[3][1]);
    }
}

// Corner term + final combine. One wave.
// sum(G) = sum over r in {0,1,H-2,H-1}, c in {0,1,W-2,W-1} of wr*wc*B(r,c),
// w = -1 at {0,1}, +1 at {n-2,n-1}; B = 3x3 gaussian (reflect-101) of d=t-p.
__global__ void finalize(const float* __restrict__ pred,
                         const float* __restrict__ target,
                         const double* __restrict__ acc,
                         float* __restrict__ out) {
    const int tid = threadIdx.x;
    float y = 0.f;
    if (tid < 16) {
        const int rows[4] = {0, 1, H - 2, H - 1};
        const int cols[4] = {0, 1, W - 2, W - 1};
        const float g[3] = {0.25f, 0.5f, 0.25f};
        const int ri = tid >> 2, ci = tid & 3;
        const int r = rows[ri], c = cols[ci];
        float b = 0.f;
        #pragma unroll
        for (int a = -1; a <= 1; ++a) {
            #pragma unroll
            for (int e = -1; e <= 1; ++e) {
                int rr = reflect_idx(r + a, H);
                int cc = reflect_idx(c + e, W);
                float d = target[rr * W + cc] - pred[rr * W + cc];
                b += g[a + 1] * g[e + 1] * d;
            }
        }
        float sgn = ((ri < 2) ? -1.f : 1.f) * ((ci < 2) ? -1.f : 1.f);
        y = sgn * b;
    }
    #pragma unroll
    for (int off = 8; off > 0; off >>= 1) y += __shfl_down(y, off);
    if (tid == 0) {
        double mse = acc[0] / fmax(acc[1], 1.0);
        double meanG = (double)y / ((double)H * (double)W);
        out[0] = (float)(ALPHA * meanG + (1.0 - ALPHA) * mse);
    }
}

extern "C" void kernel_launch(void* const* d_in, const int* in_sizes, int n_in,
                              void* d_out, int out_size, void* d_ws, size_t ws_size,
                              hipStream_t stream) {
    const float* pred   = (const float*)d_in[0];
    const float* target = (const float*)d_in[1];
    float* out = (float*)d_out;
    double* acc = (double*)d_ws;

    hipMemsetAsync(acc, 0, 2 * sizeof(double), stream);
    mse_kernel<<<NBLK, 256, 0, stream>>>((const float4*)pred, (const float4*)target, acc);
    finalize<<<1, 64, 0, stream>>>(pred, target, acc, out);
}

// Round 3
// 142.811 us; speedup vs baseline: 2.0268x; 1.3082x over previous
//
#include <hip/hip_runtime.h>

#define H 4096
#define W 4096
#define ALPHA 0.2
#define NBLK 2048
#define ITERS 8   // 2048 blocks * 256 thr * 8 float4 = 16M floats = H*W

__device__ __forceinline__ int reflect_idx(int i, int n) {
    if (i < 0) return -i;              // reflect-101, |offset| <= 1 here
    if (i >= n) return 2 * n - 2 - i;
    return i;
}

// Blocks 0..NBLK-1: masked-MSE partials over a contiguous 2048-float4 chunk.
// Block NBLK: corner term for the analytically-collapsed conv branch.
// partial layout (floats): [2*b] = sum d^2, [2*b+1] = count, [2*NBLK] = y.
__global__ __launch_bounds__(256)
void mse_kernel(const float4* __restrict__ pred,
                const float4* __restrict__ target,
                float* __restrict__ partial) {
    const int bid = blockIdx.x;
    const int tid = threadIdx.x;

    if (bid < NBLK) {
        const int base = bid * (256 * ITERS) + tid;
        float4 t[ITERS], p[ITERS];
        #pragma unroll
        for (int k = 0; k < ITERS; ++k) t[k] = target[base + k * 256];
        #pragma unroll
        for (int k = 0; k < ITERS; ++k) p[k] = pred[base + k * 256];

        float s = 0.f, cnt = 0.f;
        #pragma unroll
        for (int k = 0; k < ITERS; ++k) {
            float4 tt = t[k], pp = p[k];
            float dx = tt.x - pp.x, dy = tt.y - pp.y;
            float dz = tt.z - pp.z, dw = tt.w - pp.w;
            if (tt.x > 0.f) { s += dx * dx; cnt += 1.f; }
            if (tt.y > 0.f) { s += dy * dy; cnt += 1.f; }
            if (tt.z > 0.f) { s += dz * dz; cnt += 1.f; }
            if (tt.w > 0.f) { s += dw * dw; cnt += 1.f; }
        }
        #pragma unroll
        for (int off = 32; off > 0; off >>= 1) {
            s   += __shfl_down(s, off);
            cnt += __shfl_down(cnt, off);
        }
        __shared__ float ws[4][2];
        const int wave = tid >> 6, lane = tid & 63;
        if (lane == 0) { ws[wave][0] = s; ws[wave][1] = cnt; }
        __syncthreads();
        if (tid == 0) {
            partial[2 * bid]     = ws[0][0] + ws[1][0] + ws[2][0] + ws[3][0];
            partial[2 * bid + 1] = ws[0][1] + ws[1][1] + ws[2][1] + ws[3][1];
        }
    } else {
        // sum(G) = sum over r in {0,1,H-2,H-1} x c in {0,1,W-2,W-1} of
        // wr*wc*B(r,c); w=-1 at {0,1}, +1 at {n-2,n-1}; B = 3x3 gauss of t-p.
        const float* pr = (const float*)pred;
        const float* tg = (const float*)target;
        float y = 0.f;
        if (tid < 16) {
            const int rows[4] = {0, 1, H - 2, H - 1};
            const int cols[4] = {0, 1, W - 2, W - 1};
            const float g[3] = {0.25f, 0.5f, 0.25f};
            const int ri = tid >> 2, ci = tid & 3;
            const int r = rows[ri], c = cols[ci];
            float b = 0.f;
            #pragma unroll
            for (int a = -1; a <= 1; ++a) {
                #pragma unroll
                for (int e = -1; e <= 1; ++e) {
                    int rr = reflect_idx(r + a, H);
                    int cc = reflect_idx(c + e, W);
                    b += g[a + 1] * g[e + 1] * (tg[rr * W + cc] - pr[rr * W + cc]);
                }
            }
            y = (((ri < 2) ? -1.f : 1.f) * ((ci < 2) ? -1.f : 1.f)) * b;
        }
        #pragma unroll
        for (int off = 8; off > 0; off >>= 1) y += __shfl_down(y, off);
        if (tid == 0) partial[2 * NBLK] = y;
    }
}

// One block: reduce 2048 (s,cnt) float2 partials + corner y -> scalar loss.
__global__ __launch_bounds__(256)
void finalize(const float* __restrict__ partial, float* __restrict__ out) {
    const int tid = threadIdx.x;
    const float2* p2 = (const float2*)partial;
    double s = 0.0, c = 0.0;
    #pragma unroll
    for (int j = 0; j < NBLK / 256; ++j) {
        float2 v = p2[tid + j * 256];
        s += (double)v.x;
        c += (double)v.y;
    }
    #pragma unroll
    for (int off = 32; off > 0; off >>= 1) {
        s += __shfl_down(s, off);
        c += __shfl_down(c, off);
    }
    __shared__ double ws[4][2];
    const int wave = tid >> 6, lane = tid & 63;
    if (lane == 0) { ws[wave][0] = s; ws[wave][1] = c; }
    __syncthreads();
    if (tid == 0) {
        double sd2 = ws[0][0] + ws[1][0] + ws[2][0] + ws[3][0];
        double cnt = ws[0][1] + ws[1][1] + ws[2][1] + ws[3][1];
        double mse = sd2 / fmax(cnt, 1.0);
        double meanG = (double)partial[2 * NBLK] / ((double)H * (double)W);
        out[0] = (float)(ALPHA * meanG + (1.0 - ALPHA) * mse);
    }
}

extern "C" void kernel_launch(void* const* d_in, const int* in_sizes, int n_in,
                              void* d_out, int out_size, void* d_ws, size_t ws_size,
                              hipStream_t stream) {
    const float* pred   = (const float*)d_in[0];
    const float* target = (const float*)d_in[1];
    float* out = (float*)d_out;
    float* partial = (float*)d_ws;   // (2*NBLK + 1) floats, all written every call

    mse_kernel<<<NBLK + 1, 256, 0, stream>>>((const float4*)pred,
                                             (const float4*)target, partial);
    finalize<<<1, 256, 0, stream>>>(partial, out);
}

// Round 4
// 142.685 us; speedup vs baseline: 2.0286x; 1.0009x over previous
//
#include <hip/hip_runtime.h>

#define H 4096
#define W 4096
#define ALPHA 0.2
#define NBLK 4096
#define ITERS 4   // 4096 blocks * 256 thr * 4 float4-pairs = 16M floats = H*W

__device__ __forceinline__ int reflect_idx(int i, int n) {
    if (i < 0) return -i;              // reflect-101, |offset| <= 1 here
    if (i >= n) return 2 * n - 2 - i;
    return i;
}

// Blocks 0..NBLK-1: masked-MSE partials over a contiguous chunk (16 KB/buffer).
// Block NBLK: corner term for the analytically-collapsed conv branch.
// partial layout (floats): [2*b] = sum d^2, [2*b+1] = count, [2*NBLK] = y.
__global__ __launch_bounds__(256)
void mse_kernel(const float4* __restrict__ pred,
                const float4* __restrict__ target,
                float* __restrict__ partial) {
    const int bid = blockIdx.x;
    const int tid = threadIdx.x;

    if (bid < NBLK) {
        const int base = bid * (256 * ITERS) + tid;
        // 8 independent loads in flight (32 data VGPRs), t/p interleaved
        float4 t0 = target[base + 0 * 256];
        float4 p0 = pred  [base + 0 * 256];
        float4 t1 = target[base + 1 * 256];
        float4 p1 = pred  [base + 1 * 256];
        float4 t2 = target[base + 2 * 256];
        float4 p2 = pred  [base + 2 * 256];
        float4 t3 = target[base + 3 * 256];
        float4 p3 = pred  [base + 3 * 256];

        float sA = 0.f, cA = 0.f, sB = 0.f, cB = 0.f;
        {
            float dx = t0.x - p0.x, dy = t0.y - p0.y, dz = t0.z - p0.z, dw = t0.w - p0.w;
            if (t0.x > 0.f) { sA += dx * dx; cA += 1.f; }
            if (t0.y > 0.f) { sB += dy * dy; cB += 1.f; }
            if (t0.z > 0.f) { sA += dz * dz; cA += 1.f; }
            if (t0.w > 0.f) { sB += dw * dw; cB += 1.f; }
        }
        {
            float dx = t1.x - p1.x, dy = t1.y - p1.y, dz = t1.z - p1.z, dw = t1.w - p1.w;
            if (t1.x > 0.f) { sA += dx * dx; cA += 1.f; }
            if (t1.y > 0.f) { sB += dy * dy; cB += 1.f; }
            if (t1.z > 0.f) { sA += dz * dz; cA += 1.f; }
            if (t1.w > 0.f) { sB += dw * dw; cB += 1.f; }
        }
        {
            float dx = t2.x - p2.x, dy = t2.y - p2.y, dz = t2.z - p2.z, dw = t2.w - p2.w;
            if (t2.x > 0.f) { sA += dx * dx; cA += 1.f; }
            if (t2.y > 0.f) { sB += dy * dy; cB += 1.f; }
            if (t2.z > 0.f) { sA += dz * dz; cA += 1.f; }
            if (t2.w > 0.f) { sB += dw * dw; cB += 1.f; }
        }
        {
            float dx = t3.x - p3.x, dy = t3.y - p3.y, dz = t3.z - p3.z, dw = t3.w - p3.w;
            if (t3.x > 0.f) { sA += dx * dx; cA += 1.f; }
            if (t3.y > 0.f) { sB += dy * dy; cB += 1.f; }
            if (t3.z > 0.f) { sA += dz * dz; cA += 1.f; }
            if (t3.w > 0.f) { sB += dw * dw; cB += 1.f; }
        }
        float s = sA + sB, cnt = cA + cB;
        #pragma unroll
        for (int off = 32; off > 0; off >>= 1) {
            s   += __shfl_down(s, off);
            cnt += __shfl_down(cnt, off);
        }
        __shared__ float ws[4][2];
        const int wave = tid >> 6, lane = tid & 63;
        if (lane == 0) { ws[wave][0] = s; ws[wave][1] = cnt; }
        __syncthreads();
        if (tid == 0) {
            partial[2 * bid]     = ws[0][0] + ws[1][0] + ws[2][0] + ws[3][0];
            partial[2 * bid + 1] = ws[0][1] + ws[1][1] + ws[2][1] + ws[3][1];
        }
    } else {
        // sum(G) = sum over r in {0,1,H-2,H-1} x c in {0,1,W-2,W-1} of
        // wr*wc*B(r,c); w=-1 at {0,1}, +1 at {n-2,n-1}; B = 3x3 gauss of t-p.
        const float* pr = (const float*)pred;
        const float* tg = (const float*)target;
        float y = 0.f;
        if (tid < 16) {
            const int rows[4] = {0, 1, H - 2, H - 1};
            const int cols[4] = {0, 1, W - 2, W - 1};
            const float g[3] = {0.25f, 0.5f, 0.25f};
            const int ri = tid >> 2, ci = tid & 3;
            const int r = rows[ri], c = cols[ci];
            float b = 0.f;
            #pragma unroll
            for (int a = -1; a <= 1; ++a) {
                #pragma unroll
                for (int e = -1; e <= 1; ++e) {
                    int rr = reflect_idx(r + a, H);
                    int cc = reflect_idx(c + e, W);
                    b += g[a + 1] * g[e + 1] * (tg[rr * W + cc] - pr[rr * W + cc]);
                }
            }
            y = (((ri < 2) ? -1.f : 1.f) * ((ci < 2) ? -1.f : 1.f)) * b;
        }
        #pragma unroll
        for (int off = 8; off > 0; off >>= 1) y += __shfl_down(y, off);
        if (tid == 0) partial[2 * NBLK] = y;
    }
}

// One block: reduce NBLK (s,cnt) float2 partials + corner y -> scalar loss.
__global__ __launch_bounds__(256)
void finalize(const float* __restrict__ partial, float* __restrict__ out) {
    const int tid = threadIdx.x;
    const float2* p2 = (const float2*)partial;
    double s = 0.0, c = 0.0;
    #pragma unroll
    for (int j = 0; j < NBLK / 256; ++j) {
        float2 v = p2[tid + j * 256];
        s += (double)v.x;
        c += (double)v.y;
    }
    #pragma unroll
    for (int off = 32; off > 0; off >>= 1) {
        s += __shfl_down(s, off);
        c += __shfl_down(c, off);
    }
    __shared__ double ws[4][2];
    const int wave = tid >> 6, lane = tid & 63;
    if (lane == 0) { ws[wave][0] = s; ws[wave][1] = c; }
    __syncthreads();
    if (tid == 0) {
        double sd2 = ws[0][0] + ws[1][0] + ws[2][0] + ws[3][0];
        double cnt = ws[0][1] + ws[1][1] + ws[2][1] + ws[3][1];
        double mse = sd2 / fmax(cnt, 1.0);
        double meanG = (double)partial[2 * NBLK] / ((double)H * (double)W);
        out[0] = (float)(ALPHA * meanG + (1.0 - ALPHA) * mse);
    }
}

extern "C" void kernel_launch(void* const* d_in, const int* in_sizes, int n_in,
                              void* d_out, int out_size, void* d_ws, size_t ws_size,
                              hipStream_t stream) {
    const float* pred   = (const float*)d_in[0];
    const float* target = (const float*)d_in[1];
    float* out = (float*)d_out;
    float* partial = (float*)d_ws;   // (2*NBLK + 1) floats, all written every call

    mse_kernel<<<NBLK + 1, 256, 0, stream>>>((const float4*)pred,
                                             (const float4*)target, partial);
    finalize<<<1, 256, 0, stream>>>(partial, out);
}